// Round 6
// baseline (304.177 us; speedup 1.0000x reference)
//
#include <hip/hip_runtime.h>

// Problem constants (GNNNet_678604833376): B=2, N=50000, D=128, E=640000
#define NNODES 50000
#define NBATCH 2
#define DIM    128
#define NEDGE  640000
#define M_TOT  (NBATCH*NNODES)   // 100000 rows for the GEMM
#define NXCD   8
#define NBL_N  196               // ceil(NNODES/256)

typedef unsigned short u16;
typedef unsigned int   u32;
typedef unsigned long long u64;

typedef __attribute__((ext_vector_type(8))) short bf16x8;   // 8 bf16 = 4 VGPRs
typedef __attribute__((ext_vector_type(4))) float f32x4;

__device__ __forceinline__ float bf2f(u16 u){ return __uint_as_float(((u32)u)<<16); }
__device__ __forceinline__ u16 f2bf(float f){
    u32 x = __float_as_uint(f);
    x += 0x7fffu + ((x>>16)&1u);   // round-to-nearest-even
    return (u16)(x>>16);
}

// ---------- histogram: per-XCD partials, L2-resident workgroup-scope atomics ----------
// part[xcc][c] accumulates (fixed24(ea) << 32) | 1.  All updates to partition
// xcc come from waves physically on XCD xcc, so L2-point atomicity suffices.
// Returned old value = this edge's rank in its (partition, column) bucket.
__global__ __launch_bounds__(256) void count_k(const int* __restrict__ ei,
                                               const float* __restrict__ ea,
                                               u64* __restrict__ part,
                                               u32* __restrict__ rankpack){
    u32 xcc = __builtin_amdgcn_s_getreg(6164) & 7u;   // HW_REG_XCC_ID
    int e = blockIdx.x*256 + threadIdx.x;
    if (e < NEDGE){
        int c = ei[NEDGE + e];
        u64 inc = (((u64)__float2uint_rn(ea[e] * 16777216.0f)) << 32) | 1ull;
        u64 old = __hip_atomic_fetch_add(&part[(size_t)xcc*NNODES + c], inc,
                                         __ATOMIC_RELAXED, __HIP_MEMORY_SCOPE_WORKGROUP);
        rankpack[e] = ((u32)old & 0xffffu) | (xcc << 16);
    }
}

// ---------- fused reduce + block-scan ----------
__global__ __launch_bounds__(256) void scan1(const u64* __restrict__ part,
                                             int* __restrict__ cnt,
                                             int* __restrict__ poff,
                                             float* __restrict__ dinv,
                                             int* colstart, int* bsum){
    __shared__ int s[256];
    int tid = threadIdx.x;
    int n = blockIdx.x*256 + tid;
    int v = 0;
    if (n < NNODES){
        int run = 0; u64 fsum = 0;
        #pragma unroll
        for (int p = 0; p < NXCD; ++p){
            u64 pv = part[(size_t)p*NNODES + n];
            poff[p*NNODES + n] = run;
            run  += (int)(pv & 0xffffffffu);
            fsum += (pv >> 32);
        }
        cnt[n] = run;
        v = run;
        float deg = 1.0f + (float)fsum * (1.0f/16777216.0f);   // deg >= 1
        dinv[n] = rsqrtf(deg);
    }
    s[tid] = v; __syncthreads();
    #pragma unroll
    for (int off = 1; off < 256; off <<= 1){
        int t = (tid >= off) ? s[tid-off] : 0;
        __syncthreads();
        s[tid] += t;
        __syncthreads();
    }
    if (n < NNODES) colstart[n] = s[tid] - v;     // exclusive within block
    if (tid == 255) bsum[blockIdx.x] = s[255];
}

// ---------- CSR bucket fill + inline bsum-scan (scan23 folded in) ----------
// Each block redundantly scans the 196 block sums in LDS; writes final
// colstartF[c] (same value from every thread touching c -> benign race).
__global__ __launch_bounds__(256) void fill_k(const int* __restrict__ ei,
                                              const float* __restrict__ ea,
                                              const float* __restrict__ dinv,
                                              const int* __restrict__ colstart,
                                              const int* __restrict__ bsum,
                                              const int* __restrict__ poff,
                                              const u32* __restrict__ rankpack,
                                              int* __restrict__ colstartF,
                                              int2* __restrict__ epack){
    __shared__ int s[256];
    __shared__ int pre[256];
    int tid = threadIdx.x;
    int v = (tid < NBL_N) ? bsum[tid] : 0;
    s[tid] = v; __syncthreads();
    #pragma unroll
    for (int off = 1; off < 256; off <<= 1){
        int t = (tid >= off) ? s[tid-off] : 0;
        __syncthreads();
        s[tid] += t;
        __syncthreads();
    }
    pre[tid] = s[tid] - v;                        // exclusive prefix of bsum
    __syncthreads();

    int e = blockIdx.x*256 + tid;
    if (e < NEDGE){
        int r = ei[e], c = ei[NEDGE + e];
        u32 rp = rankpack[e];
        int base = colstart[c] + pre[c >> 8];     // final colstart for c
        colstartF[c] = base;
        int pos = base + poff[(rp >> 16)*NNODES + c] + (int)(rp & 0xffffu);
        epack[pos] = make_int2(r, __float_as_int(dinv[r] * ea[e] * dinv[c]));
    }
}

// transpose both W (fp32) -> Wt (bf16), Wt[n][k] = W[k][n]. 128 blocks.
__global__ __launch_bounds__(256) void transposeW(const float* __restrict__ W1, u16* __restrict__ Wt1,
                                                  const float* __restrict__ W2, u16* __restrict__ Wt2){
    int i = blockIdx.x*256 + threadIdx.x;
    const float* W = (i < 16384) ? W1 : W2;
    u16* Wt       = (i < 16384) ? Wt1 : Wt2;
    int ii = i & 16383;
    int k = ii >> 7, n = ii & 127;
    Wt[n*DIM + k] = f2bf(W[ii]);
}

// ---------- GEMM: H[M,128](bf16) = A[M,128](AT->bf16) @ W[128,128] ----------
__device__ __forceinline__ bf16x8 load_frag(const float* A, size_t off){
    const float4* ap = (const float4*)(A + off);
    float4 lo = ap[0], hi = ap[1];
    bf16x8 r;
    r[0] = (short)f2bf(lo.x); r[1] = (short)f2bf(lo.y);
    r[2] = (short)f2bf(lo.z); r[3] = (short)f2bf(lo.w);
    r[4] = (short)f2bf(hi.x); r[5] = (short)f2bf(hi.y);
    r[6] = (short)f2bf(hi.z); r[7] = (short)f2bf(hi.w);
    return r;
}
__device__ __forceinline__ bf16x8 load_frag(const u16* A, size_t off){
    return *(const bf16x8*)(A + off);
}

template <typename AT>
__global__ __launch_bounds__(256) void gemm128(const AT* __restrict__ A,
                                               const u16* __restrict__ Wt,
                                               u16* __restrict__ H, int M){
    __shared__ u16 Wl[128][136];   // +8 pad keeps 16B alignment, breaks 128-stride
    int tid = threadIdx.x;
    {
        const uint4* src = (const uint4*)Wt;   // 2048 x 16B
        #pragma unroll
        for (int j = 0; j < 8; ++j){
            int g = tid + j*256;
            int n = g >> 4;
            int k = (g & 15) * 8;
            *(uint4*)&Wl[n][k] = src[g];
        }
    }
    __syncthreads();

    int wave = tid >> 6, lane = tid & 63;
    int quad = lane >> 4, r = lane & 15;
    int row0 = blockIdx.x*256 + wave*64;

    f32x4 acc[4][8];
    #pragma unroll
    for (int mt = 0; mt < 4; ++mt)
        #pragma unroll
        for (int nt = 0; nt < 8; ++nt)
            acc[mt][nt] = (f32x4){0.f,0.f,0.f,0.f};

    #pragma unroll
    for (int ks = 0; ks < 4; ++ks){
        bf16x8 af[4];
        #pragma unroll
        for (int mt = 0; mt < 4; ++mt){
            int row = row0 + mt*16 + r;
            if (row < M)
                af[mt] = load_frag(A, (size_t)row*DIM + ks*32 + quad*8);
            else
                af[mt] = (bf16x8){0,0,0,0,0,0,0,0};
        }
        #pragma unroll
        for (int nt = 0; nt < 8; ++nt){
            bf16x8 bfr = *(const bf16x8*)&Wl[nt*16 + r][ks*32 + quad*8];
            #pragma unroll
            for (int mt = 0; mt < 4; ++mt)
                acc[mt][nt] = __builtin_amdgcn_mfma_f32_16x16x32_bf16(af[mt], bfr, acc[mt][nt], 0, 0, 0);
        }
    }

    // C/D layout: col = lane&15 (=r), row = quad*4 + reg
    #pragma unroll
    for (int mt = 0; mt < 4; ++mt){
        #pragma unroll
        for (int reg = 0; reg < 4; ++reg){
            int row = row0 + mt*16 + quad*4 + reg;
            if (row < M){
                #pragma unroll
                for (int nt = 0; nt < 8; ++nt)
                    H[(size_t)row*DIM + nt*16 + r] = f2bf(acc[mt][nt][reg]);
            }
        }
    }
}

// ---------- gather-aggregate: one wave = one (node, batch), scalarized ----------
// n is wave-uniform; colstart/cnt forced to SGPR via readfirstlane so the
// epack[s+j] loads have uniform addresses (s_load, no shuffles) and H-row
// loads use scalar-base + lane*4 (saddr form). 8 loads in flight per wave.
#define EFMA(W_, V_)                                        \
    a0 = fmaf(W_, bf2f((u16)((V_) & 0xffff)), a0);          \
    a1 = fmaf(W_, bf2f((u16)((V_) >> 16)),    a1);

template <bool OUT_F32>
__global__ __launch_bounds__(256) void gather3_k(const u16* __restrict__ H,
                                                 const int2* __restrict__ epack,
                                                 const int* __restrict__ colstartF,
                                                 const int* __restrict__ cnt,
                                                 const float* __restrict__ dinv,
                                                 const float* __restrict__ bias,
                                                 void* __restrict__ out){
    int wave = threadIdx.x >> 6, lane = threadIdx.x & 63;
    int batch = blockIdx.x & 1;
    int n = (blockIdx.x >> 1)*4 + wave;
    if (n >= NNODES) return;
    const u32* Hb = (const u32*)H + (size_t)batch*NNODES*64;   // 64 u32 per row

    int c = __builtin_amdgcn_readfirstlane(cnt[n]);
    int s = (c > 0) ? __builtin_amdgcn_readfirstlane(colstartF[n]) : 0;

    float dn = dinv[n], dn2 = dn*dn;
    u32 sv = Hb[(size_t)n*64 + lane];
    float a0 = dn2*bf2f((u16)(sv & 0xffff));
    float a1 = dn2*bf2f((u16)(sv >> 16));

    const int2* ep = epack + s;
    int j = 0;
    for (; j + 8 <= c; j += 8){
        int2 e0 = ep[j+0], e1 = ep[j+1], e2 = ep[j+2], e3 = ep[j+3];
        int2 e4 = ep[j+4], e5 = ep[j+5], e6 = ep[j+6], e7 = ep[j+7];
        u32 v0 = Hb[(size_t)(u32)e0.x*64 + lane];
        u32 v1 = Hb[(size_t)(u32)e1.x*64 + lane];
        u32 v2 = Hb[(size_t)(u32)e2.x*64 + lane];
        u32 v3 = Hb[(size_t)(u32)e3.x*64 + lane];
        u32 v4 = Hb[(size_t)(u32)e4.x*64 + lane];
        u32 v5 = Hb[(size_t)(u32)e5.x*64 + lane];
        u32 v6 = Hb[(size_t)(u32)e6.x*64 + lane];
        u32 v7 = Hb[(size_t)(u32)e7.x*64 + lane];
        EFMA(__int_as_float(e0.y), v0)
        EFMA(__int_as_float(e1.y), v1)
        EFMA(__int_as_float(e2.y), v2)
        EFMA(__int_as_float(e3.y), v3)
        EFMA(__int_as_float(e4.y), v4)
        EFMA(__int_as_float(e5.y), v5)
        EFMA(__int_as_float(e6.y), v6)
        EFMA(__int_as_float(e7.y), v7)
    }
    for (; j < c; ++j){
        int2 e = ep[j];
        u32 v = Hb[(size_t)(u32)e.x*64 + lane];
        EFMA(__int_as_float(e.y), v)
    }

    float2 bb = ((const float2*)bias)[lane];
    a0 = fmaxf(a0 + bb.x, 0.f);
    a1 = fmaxf(a1 + bb.y, 0.f);
    if (OUT_F32){
        float2* O = (float2*)out;
        O[(size_t)(batch*NNODES + n)*64 + lane] = make_float2(a0, a1);
    } else {
        u32* O = (u32*)out;
        O[(size_t)(batch*NNODES + n)*64 + lane] = (u32)f2bf(a0) | ((u32)f2bf(a1) << 16);
    }
}

// ---------- launch ----------
extern "C" void kernel_launch(void* const* d_in, const int* in_sizes, int n_in,
                              void* d_out, int out_size, void* d_ws, size_t ws_size,
                              hipStream_t stream){
    const float* x  = (const float*)d_in[0];
    const int*   ei = (const int*)  d_in[1];
    const float* ea = (const float*)d_in[2];
    const float* W1 = (const float*)d_in[3];
    const float* b1 = (const float*)d_in[4];
    const float* W2 = (const float*)d_in[5];
    const float* b2 = (const float*)d_in[6];

    char* p = (char*)d_ws;
    auto alloc = [&](size_t bytes)->char*{ char* r = p; p += (bytes + 511) & ~(size_t)511; return r; };
    u64*   part     = (u64*)  alloc((size_t)NXCD*NNODES*8);   // 3.2 MB partial histograms
    u32*   rankpack = (u32*)  alloc((size_t)NEDGE*4);
    int*   poff     = (int*)  alloc((size_t)NXCD*NNODES*4);
    float* dinv     = (float*)alloc(NNODES*4);
    int*   cnt      = (int*)  alloc(NNODES*4);
    int*   colstart = (int*)  alloc(NNODES*4);
    int*   colstartF= (int*)  alloc(NNODES*4);
    int*   bsum     = (int*)  alloc(1024);
    int2*  epack    = (int2*) alloc((size_t)NEDGE*8);
    u16*   Wt1      = (u16*)  alloc(DIM*DIM*2);
    u16*   Wt2      = (u16*)  alloc(DIM*DIM*2);
    u16*   h        = (u16*)  alloc((size_t)M_TOT*DIM*2);   // bf16 intermediates
    u16*   o1       = (u16*)  alloc((size_t)M_TOT*DIM*2);   // bf16 activations

    const int NBL_E = (NEDGE  + 255)/256;
    const int NTILE = (M_TOT + 255)/256;    // 391
    const int NBL_G = 2*((NNODES + 3)/4);   // 25000 (node-quad x batch)

    hipMemsetAsync(part, 0, (size_t)NXCD*NNODES*8, stream);
    transposeW<<<128, 256, 0, stream>>>(W1, Wt1, W2, Wt2);
    count_k<<<NBL_E, 256, 0, stream>>>(ei, ea, part, rankpack);
    scan1  <<<NBL_N, 256, 0, stream>>>(part, cnt, poff, dinv, colstart, bsum);
    fill_k <<<NBL_E, 256, 0, stream>>>(ei, ea, dinv, colstart, bsum, poff, rankpack, colstartF, epack);

    gemm128<float><<<NTILE, 256, 0, stream>>>(x, Wt1, h, M_TOT);
    gather3_k<false><<<NBL_G, 256, 0, stream>>>(h, epack, colstartF, cnt, dinv, b1, o1);
    gemm128<u16>  <<<NTILE, 256, 0, stream>>>(o1, Wt2, h, M_TOT);
    gather3_k<true> <<<NBL_G, 256, 0, stream>>>(h, epack, colstartF, cnt, dinv, b2, d_out);
}

// Round 7
// 296.663 us; speedup vs baseline: 1.0253x; 1.0253x over previous
//
#include <hip/hip_runtime.h>

// Problem constants (GNNNet_678604833376): B=2, N=50000, D=128, E=640000
#define NNODES 50000
#define NBATCH 2
#define DIM    128
#define NEDGE  640000
#define M_TOT  (NBATCH*NNODES)   // 100000 rows for the GEMM
#define NXCD   8
#define NBL_N  196               // ceil(NNODES/256)

typedef unsigned short u16;
typedef unsigned int   u32;
typedef unsigned long long u64;

typedef __attribute__((ext_vector_type(8))) short bf16x8;   // 8 bf16 = 4 VGPRs
typedef __attribute__((ext_vector_type(4))) float f32x4;

__device__ __forceinline__ float bf2f(u16 u){ return __uint_as_float(((u32)u)<<16); }
__device__ __forceinline__ u16 f2bf(float f){
    u32 x = __float_as_uint(f);
    x += 0x7fffu + ((x>>16)&1u);   // round-to-nearest-even
    return (u16)(x>>16);
}

// ---------- histogram: per-XCD partials, L2-resident workgroup-scope atomics ----------
__global__ __launch_bounds__(256) void count_k(const int* __restrict__ ei,
                                               const float* __restrict__ ea,
                                               u64* __restrict__ part,
                                               u32* __restrict__ rankpack){
    u32 xcc = __builtin_amdgcn_s_getreg(6164) & 7u;   // HW_REG_XCC_ID
    int e = blockIdx.x*256 + threadIdx.x;
    if (e < NEDGE){
        int c = ei[NEDGE + e];
        u64 inc = (((u64)__float2uint_rn(ea[e] * 16777216.0f)) << 32) | 1ull;
        u64 old = __hip_atomic_fetch_add(&part[(size_t)xcc*NNODES + c], inc,
                                         __ATOMIC_RELAXED, __HIP_MEMORY_SCOPE_WORKGROUP);
        rankpack[e] = ((u32)old & 0xffffu) | (xcc << 16);
    }
}

// ---------- fused reduce + block-scan ----------
__global__ __launch_bounds__(256) void scan1(const u64* __restrict__ part,
                                             int* __restrict__ cnt,
                                             int* __restrict__ poff,
                                             float* __restrict__ dinv,
                                             int* colstart, int* bsum){
    __shared__ int s[256];
    int tid = threadIdx.x;
    int n = blockIdx.x*256 + tid;
    int v = 0;
    if (n < NNODES){
        int run = 0; u64 fsum = 0;
        #pragma unroll
        for (int p = 0; p < NXCD; ++p){
            u64 pv = part[(size_t)p*NNODES + n];
            poff[p*NNODES + n] = run;
            run  += (int)(pv & 0xffffffffu);
            fsum += (pv >> 32);
        }
        cnt[n] = run;
        v = run;
        float deg = 1.0f + (float)fsum * (1.0f/16777216.0f);   // deg >= 1
        dinv[n] = rsqrtf(deg);
    }
    s[tid] = v; __syncthreads();
    #pragma unroll
    for (int off = 1; off < 256; off <<= 1){
        int t = (tid >= off) ? s[tid-off] : 0;
        __syncthreads();
        s[tid] += t;
        __syncthreads();
    }
    if (n < NNODES) colstart[n] = s[tid] - v;     // exclusive within block
    if (tid == 255) bsum[blockIdx.x] = s[255];
}

// ---------- CSR bucket fill + inline bsum-scan ----------
// epk[pos] = row | (bf16(norm) << 16)   (row < 50000 fits in 16 bits)
__global__ __launch_bounds__(256) void fill_k(const int* __restrict__ ei,
                                              const float* __restrict__ ea,
                                              const float* __restrict__ dinv,
                                              const int* __restrict__ colstart,
                                              const int* __restrict__ bsum,
                                              const int* __restrict__ poff,
                                              const u32* __restrict__ rankpack,
                                              int* __restrict__ colstartF,
                                              u32* __restrict__ epk){
    __shared__ int s[256];
    __shared__ int pre[256];
    int tid = threadIdx.x;
    int v = (tid < NBL_N) ? bsum[tid] : 0;
    s[tid] = v; __syncthreads();
    #pragma unroll
    for (int off = 1; off < 256; off <<= 1){
        int t = (tid >= off) ? s[tid-off] : 0;
        __syncthreads();
        s[tid] += t;
        __syncthreads();
    }
    pre[tid] = s[tid] - v;                        // exclusive prefix of bsum
    __syncthreads();

    int e = blockIdx.x*256 + tid;
    if (e < NEDGE){
        int r = ei[e], c = ei[NEDGE + e];
        u32 rp = rankpack[e];
        int base = colstart[c] + pre[c >> 8];     // final colstart for c
        colstartF[c] = base;
        int pos = base + poff[(rp >> 16)*NNODES + c] + (int)(rp & 0xffffu);
        float w = dinv[r] * ea[e] * dinv[c];
        epk[pos] = (u32)r | ((u32)f2bf(w) << 16);
    }
}

// transpose both W (fp32) -> Wt (bf16), Wt[n][k] = W[k][n]. 128 blocks.
__global__ __launch_bounds__(256) void transposeW(const float* __restrict__ W1, u16* __restrict__ Wt1,
                                                  const float* __restrict__ W2, u16* __restrict__ Wt2){
    int i = blockIdx.x*256 + threadIdx.x;
    const float* W = (i < 16384) ? W1 : W2;
    u16* Wt       = (i < 16384) ? Wt1 : Wt2;
    int ii = i & 16383;
    int k = ii >> 7, n = ii & 127;
    Wt[n*DIM + k] = f2bf(W[ii]);
}

// ---------- GEMM: H[M,128](bf16) = A[M,128](AT->bf16) @ W[128,128] ----------
__device__ __forceinline__ bf16x8 load_frag(const float* A, size_t off){
    const float4* ap = (const float4*)(A + off);
    float4 lo = ap[0], hi = ap[1];
    bf16x8 r;
    r[0] = (short)f2bf(lo.x); r[1] = (short)f2bf(lo.y);
    r[2] = (short)f2bf(lo.z); r[3] = (short)f2bf(lo.w);
    r[4] = (short)f2bf(hi.x); r[5] = (short)f2bf(hi.y);
    r[6] = (short)f2bf(hi.z); r[7] = (short)f2bf(hi.w);
    return r;
}
__device__ __forceinline__ bf16x8 load_frag(const u16* A, size_t off){
    return *(const bf16x8*)(A + off);
}

template <typename AT>
__global__ __launch_bounds__(256) void gemm128(const AT* __restrict__ A,
                                               const u16* __restrict__ Wt,
                                               u16* __restrict__ H, int M){
    __shared__ u16 Wl[128][136];   // +8 pad keeps 16B alignment, breaks 128-stride
    int tid = threadIdx.x;
    {
        const uint4* src = (const uint4*)Wt;   // 2048 x 16B
        #pragma unroll
        for (int j = 0; j < 8; ++j){
            int g = tid + j*256;
            int n = g >> 4;
            int k = (g & 15) * 8;
            *(uint4*)&Wl[n][k] = src[g];
        }
    }
    __syncthreads();

    int wave = tid >> 6, lane = tid & 63;
    int quad = lane >> 4, r = lane & 15;
    int row0 = blockIdx.x*256 + wave*64;

    f32x4 acc[4][8];
    #pragma unroll
    for (int mt = 0; mt < 4; ++mt)
        #pragma unroll
        for (int nt = 0; nt < 8; ++nt)
            acc[mt][nt] = (f32x4){0.f,0.f,0.f,0.f};

    #pragma unroll
    for (int ks = 0; ks < 4; ++ks){
        bf16x8 af[4];
        #pragma unroll
        for (int mt = 0; mt < 4; ++mt){
            int row = row0 + mt*16 + r;
            if (row < M)
                af[mt] = load_frag(A, (size_t)row*DIM + ks*32 + quad*8);
            else
                af[mt] = (bf16x8){0,0,0,0,0,0,0,0};
        }
        #pragma unroll
        for (int nt = 0; nt < 8; ++nt){
            bf16x8 bfr = *(const bf16x8*)&Wl[nt*16 + r][ks*32 + quad*8];
            #pragma unroll
            for (int mt = 0; mt < 4; ++mt)
                acc[mt][nt] = __builtin_amdgcn_mfma_f32_16x16x32_bf16(af[mt], bfr, acc[mt][nt], 0, 0, 0);
        }
    }

    // C/D layout: col = lane&15 (=r), row = quad*4 + reg
    #pragma unroll
    for (int mt = 0; mt < 4; ++mt){
        #pragma unroll
        for (int reg = 0; reg < 4; ++reg){
            int row = row0 + mt*16 + quad*4 + reg;
            if (row < M){
                #pragma unroll
                for (int nt = 0; nt < 8; ++nt)
                    H[(size_t)row*DIM + nt*16 + r] = f2bf(acc[mt][nt][reg]);
            }
        }
    }
}

// ---------- gather-aggregate: one wave = one (node, batch) ----------
// Per-lane metadata chunk load (1 u32/edge) + shuffle; 2-deep software
// pipeline (ping-pong buffers) keeps up to 16 H-row loads in flight.
// Weight = bf16 in metadata high half: w = uint_as_float(m & 0xffff0000).
#define GATHER_ISSUE(MB_, VB_, JB_)                                      \
    _Pragma("unroll")                                                    \
    for (int k = 0; k < 8; ++k){                                         \
        MB_[k] = __shfl(em, (JB_) + k);                                  \
        VB_[k] = Hb[(size_t)(MB_[k] & 0xffffu)*64 + lane];               \
    }
#define GATHER_CONSUME(MB_, VB_)                                         \
    _Pragma("unroll")                                                    \
    for (int k = 0; k < 8; ++k){                                         \
        float w = __uint_as_float(MB_[k] & 0xffff0000u);                 \
        a0 = fmaf(w, __uint_as_float(VB_[k] << 16), a0);                 \
        a1 = fmaf(w, __uint_as_float(VB_[k] & 0xffff0000u), a1);         \
    }

template <bool OUT_F32>
__global__ __launch_bounds__(256) void gather4_k(const u16* __restrict__ H,
                                                 const u32* __restrict__ epk,
                                                 const int* __restrict__ colstartF,
                                                 const int* __restrict__ cnt,
                                                 const float* __restrict__ dinv,
                                                 const float* __restrict__ bias,
                                                 void* __restrict__ out){
    int wave = threadIdx.x >> 6, lane = threadIdx.x & 63;
    int batch = blockIdx.x & 1;
    int n = (blockIdx.x >> 1)*4 + wave;
    if (n >= NNODES) return;
    const u32* Hb = (const u32*)H + (size_t)batch*NNODES*64;   // 64 u32 per row

    float dn = dinv[n], dn2 = dn*dn;
    u32 sv = Hb[(size_t)n*64 + lane];
    float a0 = dn2*bf2f((u16)(sv & 0xffff));
    float a1 = dn2*bf2f((u16)(sv >> 16));

    int s = colstartF[n], c = cnt[n];
    for (int base = 0; base < c; base += 64){
        int m = min(64, c - base);
        u32 em = 0;                                // pad: row 0, weight +0.0f
        if (lane < m) em = epk[s + base + lane];

        u32 mA[8], vA[8], mB[8], vB[8];
        GATHER_ISSUE(mA, vA, 0)
        bool useA = true;
        for (int j = 0; j < m; j += 8){
            int jn = j + 8;
            if (useA){
                if (jn < m){ GATHER_ISSUE(mB, vB, jn) }
                GATHER_CONSUME(mA, vA)
            } else {
                if (jn < m){ GATHER_ISSUE(mA, vA, jn) }
                GATHER_CONSUME(mB, vB)
            }
            useA = !useA;
        }
    }

    float2 bb = ((const float2*)bias)[lane];
    a0 = fmaxf(a0 + bb.x, 0.f);
    a1 = fmaxf(a1 + bb.y, 0.f);
    if (OUT_F32){
        float2* O = (float2*)out;
        O[(size_t)(batch*NNODES + n)*64 + lane] = make_float2(a0, a1);
    } else {
        u32* O = (u32*)out;
        O[(size_t)(batch*NNODES + n)*64 + lane] = (u32)f2bf(a0) | ((u32)f2bf(a1) << 16);
    }
}

// ---------- launch ----------
extern "C" void kernel_launch(void* const* d_in, const int* in_sizes, int n_in,
                              void* d_out, int out_size, void* d_ws, size_t ws_size,
                              hipStream_t stream){
    const float* x  = (const float*)d_in[0];
    const int*   ei = (const int*)  d_in[1];
    const float* ea = (const float*)d_in[2];
    const float* W1 = (const float*)d_in[3];
    const float* b1 = (const float*)d_in[4];
    const float* W2 = (const float*)d_in[5];
    const float* b2 = (const float*)d_in[6];

    char* p = (char*)d_ws;
    auto alloc = [&](size_t bytes)->char*{ char* r = p; p += (bytes + 511) & ~(size_t)511; return r; };
    u64*   part     = (u64*)  alloc((size_t)NXCD*NNODES*8);   // 3.2 MB partial histograms
    u32*   rankpack = (u32*)  alloc((size_t)NEDGE*4);
    int*   poff     = (int*)  alloc((size_t)NXCD*NNODES*4);
    float* dinv     = (float*)alloc(NNODES*4);
    int*   cnt      = (int*)  alloc(NNODES*4);
    int*   colstart = (int*)  alloc(NNODES*4);
    int*   colstartF= (int*)  alloc(NNODES*4);
    int*   bsum     = (int*)  alloc(1024);
    u32*   epk      = (u32*)  alloc((size_t)NEDGE*4);
    u16*   Wt1      = (u16*)  alloc(DIM*DIM*2);
    u16*   Wt2      = (u16*)  alloc(DIM*DIM*2);
    u16*   h        = (u16*)  alloc((size_t)M_TOT*DIM*2);   // bf16 intermediates
    u16*   o1       = (u16*)  alloc((size_t)M_TOT*DIM*2);   // bf16 activations

    const int NBL_E = (NEDGE  + 255)/256;
    const int NTILE = (M_TOT + 255)/256;    // 391
    const int NBL_G = 2*((NNODES + 3)/4);   // 25000 (node-quad x batch)

    hipMemsetAsync(part, 0, (size_t)NXCD*NNODES*8, stream);
    transposeW<<<128, 256, 0, stream>>>(W1, Wt1, W2, Wt2);
    count_k<<<NBL_E, 256, 0, stream>>>(ei, ea, part, rankpack);
    scan1  <<<NBL_N, 256, 0, stream>>>(part, cnt, poff, dinv, colstart, bsum);
    fill_k <<<NBL_E, 256, 0, stream>>>(ei, ea, dinv, colstart, bsum, poff, rankpack, colstartF, epk);

    gemm128<float><<<NTILE, 256, 0, stream>>>(x, Wt1, h, M_TOT);
    gather4_k<false><<<NBL_G, 256, 0, stream>>>(h, epk, colstartF, cnt, dinv, b1, o1);
    gemm128<u16>  <<<NTILE, 256, 0, stream>>>(o1, Wt2, h, M_TOT);
    gather4_k<true> <<<NBL_G, 256, 0, stream>>>(h, epk, colstartF, cnt, dinv, b2, d_out);
}

// Round 8
// 284.795 us; speedup vs baseline: 1.0681x; 1.0417x over previous
//
#include <hip/hip_runtime.h>

// Problem constants (GNNNet_678604833376): B=2, N=50000, D=128, E=640000
#define NNODES 50000
#define NBATCH 2
#define DIM    128
#define NEDGE  640000
#define M_TOT  (NBATCH*NNODES)   // 100000 rows for the GEMM
#define NXCD   8
#define NBL_N  196               // ceil(NNODES/256)

typedef unsigned short u16;
typedef unsigned int   u32;
typedef unsigned long long u64;

typedef __attribute__((ext_vector_type(8))) short bf16x8;   // 8 bf16 = 4 VGPRs
typedef __attribute__((ext_vector_type(4))) float f32x4;

__device__ __forceinline__ float bf2f(u16 u){ return __uint_as_float(((u32)u)<<16); }
__device__ __forceinline__ u16 f2bf(float f){
    u32 x = __float_as_uint(f);
    x += 0x7fffu + ((x>>16)&1u);   // round-to-nearest-even
    return (u16)(x>>16);
}

// ---------- histogram: per-XCD partials, L2-resident workgroup-scope atomics ----------
__global__ __launch_bounds__(256) void count_k(const int* __restrict__ ei,
                                               const float* __restrict__ ea,
                                               u64* __restrict__ part,
                                               u32* __restrict__ rankpack){
    u32 xcc = __builtin_amdgcn_s_getreg(6164) & 7u;   // HW_REG_XCC_ID
    int e = blockIdx.x*256 + threadIdx.x;
    if (e < NEDGE){
        int c = ei[NEDGE + e];
        u64 inc = (((u64)__float2uint_rn(ea[e] * 16777216.0f)) << 32) | 1ull;
        u64 old = __hip_atomic_fetch_add(&part[(size_t)xcc*NNODES + c], inc,
                                         __ATOMIC_RELAXED, __HIP_MEMORY_SCOPE_WORKGROUP);
        rankpack[e] = ((u32)old & 0xffffu) | (xcc << 16);
    }
}

// ---------- fused reduce + block-scan ----------
__global__ __launch_bounds__(256) void scan1(const u64* __restrict__ part,
                                             int* __restrict__ cnt,
                                             int* __restrict__ poff,
                                             float* __restrict__ dinv,
                                             int* colstart, int* bsum){
    __shared__ int s[256];
    int tid = threadIdx.x;
    int n = blockIdx.x*256 + tid;
    int v = 0;
    if (n < NNODES){
        int run = 0; u64 fsum = 0;
        #pragma unroll
        for (int p = 0; p < NXCD; ++p){
            u64 pv = part[(size_t)p*NNODES + n];
            poff[p*NNODES + n] = run;
            run  += (int)(pv & 0xffffffffu);
            fsum += (pv >> 32);
        }
        cnt[n] = run;
        v = run;
        float deg = 1.0f + (float)fsum * (1.0f/16777216.0f);   // deg >= 1
        dinv[n] = rsqrtf(deg);
    }
    s[tid] = v; __syncthreads();
    #pragma unroll
    for (int off = 1; off < 256; off <<= 1){
        int t = (tid >= off) ? s[tid-off] : 0;
        __syncthreads();
        s[tid] += t;
        __syncthreads();
    }
    if (n < NNODES) colstart[n] = s[tid] - v;     // exclusive within block
    if (tid == 255) bsum[blockIdx.x] = s[255];
}

// ---------- CSR bucket fill + inline bsum-scan ----------
// epk[pos] = row | (bf16(norm) << 16)   (row < 50000 fits in 16 bits)
__global__ __launch_bounds__(256) void fill_k(const int* __restrict__ ei,
                                              const float* __restrict__ ea,
                                              const float* __restrict__ dinv,
                                              const int* __restrict__ colstart,
                                              const int* __restrict__ bsum,
                                              const int* __restrict__ poff,
                                              const u32* __restrict__ rankpack,
                                              int* __restrict__ colstartF,
                                              u32* __restrict__ epk){
    __shared__ int s[256];
    __shared__ int pre[256];
    int tid = threadIdx.x;
    int v = (tid < NBL_N) ? bsum[tid] : 0;
    s[tid] = v; __syncthreads();
    #pragma unroll
    for (int off = 1; off < 256; off <<= 1){
        int t = (tid >= off) ? s[tid-off] : 0;
        __syncthreads();
        s[tid] += t;
        __syncthreads();
    }
    pre[tid] = s[tid] - v;                        // exclusive prefix of bsum
    __syncthreads();

    int e = blockIdx.x*256 + tid;
    if (e < NEDGE){
        int r = ei[e], c = ei[NEDGE + e];
        u32 rp = rankpack[e];
        int base = colstart[c] + pre[c >> 8];     // final colstart for c
        colstartF[c] = base;
        int pos = base + poff[(rp >> 16)*NNODES + c] + (int)(rp & 0xffffu);
        float w = dinv[r] * ea[e] * dinv[c];
        epk[pos] = (u32)r | ((u32)f2bf(w) << 16);
    }
}

// transpose both W (fp32) -> Wt (bf16), Wt[n][k] = W[k][n]. 128 blocks.
__global__ __launch_bounds__(256) void transposeW(const float* __restrict__ W1, u16* __restrict__ Wt1,
                                                  const float* __restrict__ W2, u16* __restrict__ Wt2){
    int i = blockIdx.x*256 + threadIdx.x;
    const float* W = (i < 16384) ? W1 : W2;
    u16* Wt       = (i < 16384) ? Wt1 : Wt2;
    int ii = i & 16383;
    int k = ii >> 7, n = ii & 127;
    Wt[n*DIM + k] = f2bf(W[ii]);
}

// ---------- GEMM: H[M,128](bf16) = A[M,128](AT->bf16) @ W[128,128] ----------
__device__ __forceinline__ bf16x8 load_frag(const float* A, size_t off){
    const float4* ap = (const float4*)(A + off);
    float4 lo = ap[0], hi = ap[1];
    bf16x8 r;
    r[0] = (short)f2bf(lo.x); r[1] = (short)f2bf(lo.y);
    r[2] = (short)f2bf(lo.z); r[3] = (short)f2bf(lo.w);
    r[4] = (short)f2bf(hi.x); r[5] = (short)f2bf(hi.y);
    r[6] = (short)f2bf(hi.z); r[7] = (short)f2bf(hi.w);
    return r;
}
__device__ __forceinline__ bf16x8 load_frag(const u16* A, size_t off){
    return *(const bf16x8*)(A + off);
}

template <typename AT>
__global__ __launch_bounds__(256) void gemm128(const AT* __restrict__ A,
                                               const u16* __restrict__ Wt,
                                               u16* __restrict__ H, int M){
    __shared__ u16 Wl[128][136];   // +8 pad keeps 16B alignment, breaks 128-stride
    int tid = threadIdx.x;
    {
        const uint4* src = (const uint4*)Wt;   // 2048 x 16B
        #pragma unroll
        for (int j = 0; j < 8; ++j){
            int g = tid + j*256;
            int n = g >> 4;
            int k = (g & 15) * 8;
            *(uint4*)&Wl[n][k] = src[g];
        }
    }
    __syncthreads();

    int wave = tid >> 6, lane = tid & 63;
    int quad = lane >> 4, r = lane & 15;
    int row0 = blockIdx.x*256 + wave*64;

    f32x4 acc[4][8];
    #pragma unroll
    for (int mt = 0; mt < 4; ++mt)
        #pragma unroll
        for (int nt = 0; nt < 8; ++nt)
            acc[mt][nt] = (f32x4){0.f,0.f,0.f,0.f};

    #pragma unroll
    for (int ks = 0; ks < 4; ++ks){
        bf16x8 af[4];
        #pragma unroll
        for (int mt = 0; mt < 4; ++mt){
            int row = row0 + mt*16 + r;
            if (row < M)
                af[mt] = load_frag(A, (size_t)row*DIM + ks*32 + quad*8);
            else
                af[mt] = (bf16x8){0,0,0,0,0,0,0,0};
        }
        #pragma unroll
        for (int nt = 0; nt < 8; ++nt){
            bf16x8 bfr = *(const bf16x8*)&Wl[nt*16 + r][ks*32 + quad*8];
            #pragma unroll
            for (int mt = 0; mt < 4; ++mt)
                acc[mt][nt] = __builtin_amdgcn_mfma_f32_16x16x32_bf16(af[mt], bfr, acc[mt][nt], 0, 0, 0);
        }
    }

    // C/D layout: col = lane&15 (=r), row = quad*4 + reg
    #pragma unroll
    for (int mt = 0; mt < 4; ++mt){
        #pragma unroll
        for (int reg = 0; reg < 4; ++reg){
            int row = row0 + mt*16 + quad*4 + reg;
            if (row < M){
                #pragma unroll
                for (int nt = 0; nt < 8; ++nt)
                    H[(size_t)row*DIM + nt*16 + r] = f2bf(acc[mt][nt][reg]);
            }
        }
    }
}

// ---------- gather-aggregate: one wave = one (node, batch), 2 edges per load ----------
// Lane ell loads dwordx2: lanes 0-31 cover edge j's 256B row, lanes 32-63 edge
// j+1's. 1 VMEM + 1 shuffle per 2 edges. Lane accumulates cols [4*(ell&31)..+4);
// final shfl_xor(32) fold merges halves; lanes 0-31 write the row.
template <bool OUT_F32>
__global__ __launch_bounds__(256) void gather5_k(const u16* __restrict__ H,
                                                 const u32* __restrict__ epk,
                                                 const int* __restrict__ colstartF,
                                                 const int* __restrict__ cnt,
                                                 const float* __restrict__ dinv,
                                                 const float* __restrict__ bias,
                                                 void* __restrict__ out){
    int wave = threadIdx.x >> 6, lane = threadIdx.x & 63;
    int batch = blockIdx.x & 1;
    int n = (blockIdx.x >> 1)*4 + wave;
    if (n >= NNODES) return;
    const char* Hb = (const char*)H + (size_t)batch*NNODES*256;
    int half = lane >> 5;          // which edge of the pair this lane serves
    int sub  = lane & 31;          // 8B sub-chunk within the 256B row

    float a0, a1, a2, a3;
    {
        uint2 sv = *(const uint2*)(Hb + (size_t)n*256 + sub*8);
        float dn = dinv[n];
        float dn2 = half ? 0.f : dn*dn;          // half 1 inits 0 (fold adds)
        a0 = dn2*__uint_as_float(sv.x << 16);
        a1 = dn2*__uint_as_float(sv.x & 0xffff0000u);
        a2 = dn2*__uint_as_float(sv.y << 16);
        a3 = dn2*__uint_as_float(sv.y & 0xffff0000u);
    }

    int s = colstartF[n], c = cnt[n];
    for (int base = 0; base < c; base += 64){
        int m = min(64, c - base);
        u32 em = 0;                               // pad: row 0, weight +0.0f
        if (lane < m) em = epk[s + base + lane];
        for (int j = 0; j < m; j += 16){          // 8 groups x 2 edges
            #pragma unroll
            for (int g = 0; g < 8; ++g){
                u32 me = __shfl(em, j + 2*g + half);   // max idx j+15 <= 63
                uint2 v = *(const uint2*)(Hb + (size_t)(me & 0xffffu)*256 + sub*8);
                float w = __uint_as_float(me & 0xffff0000u);
                a0 = fmaf(w, __uint_as_float(v.x << 16), a0);
                a1 = fmaf(w, __uint_as_float(v.x & 0xffff0000u), a1);
                a2 = fmaf(w, __uint_as_float(v.y << 16), a2);
                a3 = fmaf(w, __uint_as_float(v.y & 0xffff0000u), a3);
            }
        }
    }

    // fold the two half-wave partials
    a0 += __shfl_xor(a0, 32);
    a1 += __shfl_xor(a1, 32);
    a2 += __shfl_xor(a2, 32);
    a3 += __shfl_xor(a3, 32);

    if (lane < 32){
        float4 bb = ((const float4*)bias)[sub];   // cols [4*sub .. 4*sub+4)
        a0 = fmaxf(a0 + bb.x, 0.f);
        a1 = fmaxf(a1 + bb.y, 0.f);
        a2 = fmaxf(a2 + bb.z, 0.f);
        a3 = fmaxf(a3 + bb.w, 0.f);
        if (OUT_F32){
            float* O = (float*)out + (size_t)(batch*NNODES + n)*DIM;
            *(float4*)(O + sub*4) = make_float4(a0, a1, a2, a3);
        } else {
            char* O = (char*)out + (size_t)(batch*NNODES + n)*256;
            uint2 pk;
            pk.x = (u32)f2bf(a0) | ((u32)f2bf(a1) << 16);
            pk.y = (u32)f2bf(a2) | ((u32)f2bf(a3) << 16);
            *(uint2*)(O + sub*8) = pk;
        }
    }
}

// ---------- launch ----------
extern "C" void kernel_launch(void* const* d_in, const int* in_sizes, int n_in,
                              void* d_out, int out_size, void* d_ws, size_t ws_size,
                              hipStream_t stream){
    const float* x  = (const float*)d_in[0];
    const int*   ei = (const int*)  d_in[1];
    const float* ea = (const float*)d_in[2];
    const float* W1 = (const float*)d_in[3];
    const float* b1 = (const float*)d_in[4];
    const float* W2 = (const float*)d_in[5];
    const float* b2 = (const float*)d_in[6];

    char* p = (char*)d_ws;
    auto alloc = [&](size_t bytes)->char*{ char* r = p; p += (bytes + 511) & ~(size_t)511; return r; };
    u64*   part     = (u64*)  alloc((size_t)NXCD*NNODES*8);   // 3.2 MB partial histograms
    u32*   rankpack = (u32*)  alloc((size_t)NEDGE*4);
    int*   poff     = (int*)  alloc((size_t)NXCD*NNODES*4);
    float* dinv     = (float*)alloc(NNODES*4);
    int*   cnt      = (int*)  alloc(NNODES*4);
    int*   colstart = (int*)  alloc(NNODES*4);
    int*   colstartF= (int*)  alloc(NNODES*4);
    int*   bsum     = (int*)  alloc(1024);
    u32*   epk      = (u32*)  alloc((size_t)NEDGE*4);
    u16*   Wt1      = (u16*)  alloc(DIM*DIM*2);
    u16*   Wt2      = (u16*)  alloc(DIM*DIM*2);
    u16*   h        = (u16*)  alloc((size_t)M_TOT*DIM*2);   // bf16 intermediates
    u16*   o1       = (u16*)  alloc((size_t)M_TOT*DIM*2);   // bf16 activations

    const int NBL_E = (NEDGE  + 255)/256;
    const int NTILE = (M_TOT + 255)/256;    // 391
    const int NBL_G = 2*((NNODES + 3)/4);   // 25000 (node-quad x batch)

    hipMemsetAsync(part, 0, (size_t)NXCD*NNODES*8, stream);
    transposeW<<<128, 256, 0, stream>>>(W1, Wt1, W2, Wt2);
    count_k<<<NBL_E, 256, 0, stream>>>(ei, ea, part, rankpack);
    scan1  <<<NBL_N, 256, 0, stream>>>(part, cnt, poff, dinv, colstart, bsum);
    fill_k <<<NBL_E, 256, 0, stream>>>(ei, ea, dinv, colstart, bsum, poff, rankpack, colstartF, epk);

    gemm128<float><<<NTILE, 256, 0, stream>>>(x, Wt1, h, M_TOT);
    gather5_k<false><<<NBL_G, 256, 0, stream>>>(h, epk, colstartF, cnt, dinv, b1, o1);
    gemm128<u16>  <<<NTILE, 256, 0, stream>>>(o1, Wt2, h, M_TOT);
    gather5_k<true> <<<NBL_G, 256, 0, stream>>>(h, epk, colstartF, cnt, dinv, b2, d_out);
}

// Round 9
// 283.452 us; speedup vs baseline: 1.0731x; 1.0047x over previous
//
#include <hip/hip_runtime.h>

// Problem constants (GNNNet_678604833376): B=2, N=50000, D=128, E=640000
#define NNODES 50000
#define NBATCH 2
#define DIM    128
#define NEDGE  640000
#define M_TOT  (NBATCH*NNODES)   // 100000 rows for the GEMM
#define NXCD   8
#define NBL_N  196               // ceil(NNODES/256)

typedef unsigned short u16;
typedef unsigned int   u32;
typedef unsigned long long u64;

typedef __attribute__((ext_vector_type(8))) short bf16x8;   // 8 bf16 = 4 VGPRs
typedef __attribute__((ext_vector_type(4))) float f32x4;

__device__ __forceinline__ float bf2f(u16 u){ return __uint_as_float(((u32)u)<<16); }
__device__ __forceinline__ u16 f2bf(float f){
    u32 x = __float_as_uint(f);
    x += 0x7fffu + ((x>>16)&1u);   // round-to-nearest-even
    return (u16)(x>>16);
}

// ---------- histogram: per-XCD partials, L2-resident workgroup-scope atomics ----------
__global__ __launch_bounds__(256) void count_k(const int* __restrict__ ei,
                                               const float* __restrict__ ea,
                                               u64* __restrict__ part,
                                               u32* __restrict__ rankpack){
    u32 xcc = __builtin_amdgcn_s_getreg(6164) & 7u;   // HW_REG_XCC_ID
    int e = blockIdx.x*256 + threadIdx.x;
    if (e < NEDGE){
        int c = ei[NEDGE + e];
        u64 inc = (((u64)__float2uint_rn(ea[e] * 16777216.0f)) << 32) | 1ull;
        u64 old = __hip_atomic_fetch_add(&part[(size_t)xcc*NNODES + c], inc,
                                         __ATOMIC_RELAXED, __HIP_MEMORY_SCOPE_WORKGROUP);
        rankpack[e] = ((u32)old & 0xffffu) | (xcc << 16);
    }
}

// ---------- fused reduce + block-scan ----------
__global__ __launch_bounds__(256) void scan1(const u64* __restrict__ part,
                                             int* __restrict__ cnt,
                                             int* __restrict__ poff,
                                             float* __restrict__ dinv,
                                             int* colstart, int* bsum){
    __shared__ int s[256];
    int tid = threadIdx.x;
    int n = blockIdx.x*256 + tid;
    int v = 0;
    if (n < NNODES){
        int run = 0; u64 fsum = 0;
        #pragma unroll
        for (int p = 0; p < NXCD; ++p){
            u64 pv = part[(size_t)p*NNODES + n];
            poff[p*NNODES + n] = run;
            run  += (int)(pv & 0xffffffffu);
            fsum += (pv >> 32);
        }
        cnt[n] = run;
        v = run;
        float deg = 1.0f + (float)fsum * (1.0f/16777216.0f);   // deg >= 1
        dinv[n] = rsqrtf(deg);
    }
    s[tid] = v; __syncthreads();
    #pragma unroll
    for (int off = 1; off < 256; off <<= 1){
        int t = (tid >= off) ? s[tid-off] : 0;
        __syncthreads();
        s[tid] += t;
        __syncthreads();
    }
    if (n < NNODES) colstart[n] = s[tid] - v;     // exclusive within block
    if (tid == 255) bsum[blockIdx.x] = s[255];
}

// ---------- CSR bucket fill + inline bsum-scan ----------
// epk[pos] = row | (bf16(norm) << 16)   (row < 50000 fits in 16 bits)
__global__ __launch_bounds__(256) void fill_k(const int* __restrict__ ei,
                                              const float* __restrict__ ea,
                                              const float* __restrict__ dinv,
                                              const int* __restrict__ colstart,
                                              const int* __restrict__ bsum,
                                              const int* __restrict__ poff,
                                              const u32* __restrict__ rankpack,
                                              int* __restrict__ colstartF,
                                              u32* __restrict__ epk){
    __shared__ int s[256];
    __shared__ int pre[256];
    int tid = threadIdx.x;
    int v = (tid < NBL_N) ? bsum[tid] : 0;
    s[tid] = v; __syncthreads();
    #pragma unroll
    for (int off = 1; off < 256; off <<= 1){
        int t = (tid >= off) ? s[tid-off] : 0;
        __syncthreads();
        s[tid] += t;
        __syncthreads();
    }
    pre[tid] = s[tid] - v;                        // exclusive prefix of bsum
    __syncthreads();

    int e = blockIdx.x*256 + tid;
    if (e < NEDGE){
        int r = ei[e], c = ei[NEDGE + e];
        u32 rp = rankpack[e];
        int base = colstart[c] + pre[c >> 8];     // final colstart for c
        colstartF[c] = base;
        int pos = base + poff[(rp >> 16)*NNODES + c] + (int)(rp & 0xffffu);
        float w = dinv[r] * ea[e] * dinv[c];
        epk[pos] = (u32)r | ((u32)f2bf(w) << 16);
    }
}

// transpose both W (fp32) -> Wt (bf16), Wt[n][k] = W[k][n]; also zero part[].
__global__ __launch_bounds__(256) void transposeW(const float* __restrict__ W1, u16* __restrict__ Wt1,
                                                  const float* __restrict__ W2, u16* __restrict__ Wt2,
                                                  u64* __restrict__ part){
    int i = blockIdx.x*256 + threadIdx.x;         // 128 x 256 = 32768 threads
    const float* W = (i < 16384) ? W1 : W2;
    u16* Wt       = (i < 16384) ? Wt1 : Wt2;
    int ii = i & 16383;
    int k = ii >> 7, n = ii & 127;
    Wt[n*DIM + k] = f2bf(W[ii]);
    // zero the 8x50000 u64 histogram: 400000 u64 / 32768 thr = 13 each
    for (int z = i; z < NXCD*NNODES; z += 32768) part[z] = 0;
}

// ---------- GEMM: H(bf16) = A(AT->bf16) @ W[128,128] ----------
// PERM: store row arow (= b*N+n) to interleaved row 2n+b; else identity.
__device__ __forceinline__ bf16x8 load_frag(const float* A, size_t off){
    const float4* ap = (const float4*)(A + off);
    float4 lo = ap[0], hi = ap[1];
    bf16x8 r;
    r[0] = (short)f2bf(lo.x); r[1] = (short)f2bf(lo.y);
    r[2] = (short)f2bf(lo.z); r[3] = (short)f2bf(lo.w);
    r[4] = (short)f2bf(hi.x); r[5] = (short)f2bf(hi.y);
    r[6] = (short)f2bf(hi.z); r[7] = (short)f2bf(hi.w);
    return r;
}
__device__ __forceinline__ bf16x8 load_frag(const u16* A, size_t off){
    return *(const bf16x8*)(A + off);
}

template <typename AT, bool PERM>
__global__ __launch_bounds__(256) void gemm128(const AT* __restrict__ A,
                                               const u16* __restrict__ Wt,
                                               u16* __restrict__ H, int M){
    __shared__ u16 Wl[128][136];   // +8 pad keeps 16B alignment, breaks 128-stride
    int tid = threadIdx.x;
    {
        const uint4* src = (const uint4*)Wt;   // 2048 x 16B
        #pragma unroll
        for (int j = 0; j < 8; ++j){
            int g = tid + j*256;
            int n = g >> 4;
            int k = (g & 15) * 8;
            *(uint4*)&Wl[n][k] = src[g];
        }
    }
    __syncthreads();

    int wave = tid >> 6, lane = tid & 63;
    int quad = lane >> 4, r = lane & 15;
    int row0 = blockIdx.x*256 + wave*64;

    f32x4 acc[4][8];
    #pragma unroll
    for (int mt = 0; mt < 4; ++mt)
        #pragma unroll
        for (int nt = 0; nt < 8; ++nt)
            acc[mt][nt] = (f32x4){0.f,0.f,0.f,0.f};

    #pragma unroll
    for (int ks = 0; ks < 4; ++ks){
        bf16x8 af[4];
        #pragma unroll
        for (int mt = 0; mt < 4; ++mt){
            int row = row0 + mt*16 + r;
            if (row < M)
                af[mt] = load_frag(A, (size_t)row*DIM + ks*32 + quad*8);
            else
                af[mt] = (bf16x8){0,0,0,0,0,0,0,0};
        }
        #pragma unroll
        for (int nt = 0; nt < 8; ++nt){
            bf16x8 bfr = *(const bf16x8*)&Wl[nt*16 + r][ks*32 + quad*8];
            #pragma unroll
            for (int mt = 0; mt < 4; ++mt)
                acc[mt][nt] = __builtin_amdgcn_mfma_f32_16x16x32_bf16(af[mt], bfr, acc[mt][nt], 0, 0, 0);
        }
    }

    // C/D layout: col = lane&15 (=r), row = quad*4 + reg
    #pragma unroll
    for (int mt = 0; mt < 4; ++mt){
        #pragma unroll
        for (int reg = 0; reg < 4; ++reg){
            int row = row0 + mt*16 + quad*4 + reg;
            if (row < M){
                size_t hrow;
                if (PERM){
                    int b = (row >= NNODES);
                    int n = row - b*NNODES;
                    hrow = (size_t)(2*n + b);
                } else {
                    hrow = (size_t)row;
                }
                #pragma unroll
                for (int nt = 0; nt < 8; ++nt)
                    H[hrow*DIM + nt*16 + r] = f2bf(acc[mt][nt][reg]);
            }
        }
    }
}

// ---------- gather-aggregate: one wave = one node, BOTH batches ----------
// H interleaved: Hi[n][batch][128] bf16 -> one edge = one contiguous 512B
// wave-load (lane ell: batch = ell>>5, cols 4*(ell&31)..+3). 1 VMEM + 1 shfl
// per edge covering both batches; all 64 lanes write output (no fold).
template <bool OUT_F32>
__global__ __launch_bounds__(256) void gather6_k(const u16* __restrict__ Hi,
                                                 const u32* __restrict__ epk,
                                                 const int* __restrict__ colstartF,
                                                 const int* __restrict__ cnt,
                                                 const float* __restrict__ dinv,
                                                 const float* __restrict__ bias,
                                                 void* __restrict__ out){
    int wave = threadIdx.x >> 6, lane = threadIdx.x & 63;
    int n = blockIdx.x*4 + wave;
    if (n >= NNODES) return;
    const char* Hb = (const char*)Hi;             // row stride 512 B (both batches)

    float a0, a1, a2, a3;
    {
        uint2 sv = *(const uint2*)(Hb + (size_t)n*512 + lane*8);
        float dn = dinv[n], dn2 = dn*dn;
        a0 = dn2*__uint_as_float(sv.x << 16);
        a1 = dn2*__uint_as_float(sv.x & 0xffff0000u);
        a2 = dn2*__uint_as_float(sv.y << 16);
        a3 = dn2*__uint_as_float(sv.y & 0xffff0000u);
    }

    int s = colstartF[n], c = cnt[n];
    for (int base = 0; base < c; base += 64){
        int m = min(64, c - base);
        u32 em = 0;                               // pad: row 0, weight +0.0f
        if (lane < m) em = epk[s + base + lane];
        for (int j = 0; j < m; j += 8){           // 8 edges per iter, 8 loads in flight
            #pragma unroll
            for (int g = 0; g < 8; ++g){
                u32 me = __shfl(em, j + g);       // max idx 56+7 = 63
                uint2 v = *(const uint2*)(Hb + (size_t)(me & 0xffffu)*512 + lane*8);
                float w = __uint_as_float(me & 0xffff0000u);
                a0 = fmaf(w, __uint_as_float(v.x << 16), a0);
                a1 = fmaf(w, __uint_as_float(v.x & 0xffff0000u), a1);
                a2 = fmaf(w, __uint_as_float(v.y << 16), a2);
                a3 = fmaf(w, __uint_as_float(v.y & 0xffff0000u), a3);
            }
        }
    }

    int sub = lane & 31, b = lane >> 5;
    float4 bb = ((const float4*)bias)[sub];       // cols [4*sub .. 4*sub+4), same both batches
    a0 = fmaxf(a0 + bb.x, 0.f);
    a1 = fmaxf(a1 + bb.y, 0.f);
    a2 = fmaxf(a2 + bb.z, 0.f);
    a3 = fmaxf(a3 + bb.w, 0.f);
    if (OUT_F32){
        // de-interleave: d_out row = b*N + n (fp32)
        float* O = (float*)out + ((size_t)b*NNODES + n)*DIM + sub*4;
        *(float4*)O = make_float4(a0, a1, a2, a3);
    } else {
        // stay interleaved (bf16): row 2n+b == byte offset n*512 + lane*8
        char* O = (char*)out + (size_t)n*512 + lane*8;
        uint2 pk;
        pk.x = (u32)f2bf(a0) | ((u32)f2bf(a1) << 16);
        pk.y = (u32)f2bf(a2) | ((u32)f2bf(a3) << 16);
        *(uint2*)O = pk;
    }
}

// ---------- launch ----------
extern "C" void kernel_launch(void* const* d_in, const int* in_sizes, int n_in,
                              void* d_out, int out_size, void* d_ws, size_t ws_size,
                              hipStream_t stream){
    const float* x  = (const float*)d_in[0];
    const int*   ei = (const int*)  d_in[1];
    const float* ea = (const float*)d_in[2];
    const float* W1 = (const float*)d_in[3];
    const float* b1 = (const float*)d_in[4];
    const float* W2 = (const float*)d_in[5];
    const float* b2 = (const float*)d_in[6];

    char* p = (char*)d_ws;
    auto alloc = [&](size_t bytes)->char*{ char* r = p; p += (bytes + 511) & ~(size_t)511; return r; };
    u64*   part     = (u64*)  alloc((size_t)NXCD*NNODES*8);   // 3.2 MB partial histograms
    u32*   rankpack = (u32*)  alloc((size_t)NEDGE*4);
    int*   poff     = (int*)  alloc((size_t)NXCD*NNODES*4);
    float* dinv     = (float*)alloc(NNODES*4);
    int*   cnt      = (int*)  alloc(NNODES*4);
    int*   colstart = (int*)  alloc(NNODES*4);
    int*   colstartF= (int*)  alloc(NNODES*4);
    int*   bsum     = (int*)  alloc(1024);
    u32*   epk      = (u32*)  alloc((size_t)NEDGE*4);
    u16*   Wt1      = (u16*)  alloc(DIM*DIM*2);
    u16*   Wt2      = (u16*)  alloc(DIM*DIM*2);
    u16*   h        = (u16*)  alloc((size_t)M_TOT*DIM*2);   // bf16, batch-interleaved
    u16*   o1       = (u16*)  alloc((size_t)M_TOT*DIM*2);   // bf16, batch-interleaved

    const int NBL_E = (NEDGE  + 255)/256;
    const int NTILE = (M_TOT + 255)/256;    // 391
    const int NBL_G = (NNODES + 3)/4;       // 12500 (4 node-waves per block)

    transposeW<<<128, 256, 0, stream>>>(W1, Wt1, W2, Wt2, part);
    count_k<<<NBL_E, 256, 0, stream>>>(ei, ea, part, rankpack);
    scan1  <<<NBL_N, 256, 0, stream>>>(part, cnt, poff, dinv, colstart, bsum);
    fill_k <<<NBL_E, 256, 0, stream>>>(ei, ea, dinv, colstart, bsum, poff, rankpack, colstartF, epk);

    gemm128<float, true ><<<NTILE, 256, 0, stream>>>(x,  Wt1, h, M_TOT);
    gather6_k<false><<<NBL_G, 256, 0, stream>>>(h,  epk, colstartF, cnt, dinv, b1, o1);
    gemm128<u16,   false><<<NTILE, 256, 0, stream>>>(o1, Wt2, h, M_TOT);
    gather6_k<true ><<<NBL_G, 256, 0, stream>>>(h,  epk, colstartF, cnt, dinv, b2, d_out);
}